// Round 13
// baseline (133.243 us; speedup 1.0000x reference)
//
#include <hip/hip_runtime.h>

typedef __attribute__((ext_vector_type(8))) short short8;
typedef __attribute__((ext_vector_type(4))) float f32x4;
typedef __attribute__((ext_vector_type(4))) unsigned int uint4v;

#define HW 65536
#define NPOS 32768

__device__ __forceinline__ unsigned short f2bf(float f) {
  unsigned u = __builtin_bit_cast(unsigned, f);
  u += 0x7fffu + ((u >> 16) & 1u);
  return (unsigned short)(u >> 16);
}
__device__ __forceinline__ float bf2f(unsigned short h) {
  unsigned u = (unsigned)h << 16;
  return __builtin_bit_cast(float, u);
}
__device__ __forceinline__ int slot4(int r) { return (r ^ (r >> 2)) & 15; }
// 16B fragment from 8B-aligned LDS (row stride 136B) as two b64 reads
__device__ __forceinline__ short8 ld_e16(const unsigned short* p) {
  const uint2 a = *(const uint2*)p;
  const uint2 b = *(const uint2*)(p + 4);
  uint4v u = {a.x, a.y, b.x, b.y};
  return __builtin_bit_cast(short8, u);
}

// ---------------------------------------------------------------------------
// k0: split conv weights to bf16 hi/lo; rows 0-31 = phi, 32-63 = g.
// ---------------------------------------------------------------------------
__global__ __launch_bounds__(256) void k0_prep(
    const float* __restrict__ wphi, const float* __restrict__ wg,
    unsigned short* __restrict__ Whi, unsigned short* __restrict__ Wlo)
{
  const int idx = blockIdx.x * 256 + threadIdx.x;  // 4096 total
  const int u = idx >> 6, c = idx & 63;
  const float w = (u < 32) ? wphi[u * 64 + c] : wg[(u - 32) * 64 + c];
  const unsigned short h = f2bf(w);
  Whi[idx] = h;
  Wlo[idx] = f2bf(w - bf2f(h));
}

// ---------------------------------------------------------------------------
// k1: FUSED conv + exp + att, atomic-free. Single-buffered E (17.4 KB LDS
// -> 9 blocks/CU LDS-cap vs 4 for double-buffer) and grid (256,8) = 2048
// blocks x 2 subtiles (~6 resident blocks/CU at VGPR 84) so independent
// blocks interleave phases and hide each other's barrier drains.
// Block = 4 waves / 256 thr, owns 128 view-cols = 2 subtiles of 64.
// Two barriers per subtile (E-write complete; att-reads complete).
// ---------------------------------------------------------------------------
__global__ __launch_bounds__(256) void k1_att(
    const float* __restrict__ x, const unsigned short* __restrict__ Whi,
    const unsigned short* __restrict__ Wlo, float* __restrict__ attP,
    float2* __restrict__ spart)
{
  __shared__ unsigned short E[128 * 68];   // rows 0-63 Ep, 64-127 Eg (view rows)
  __shared__ float2 rbuf[4];

  const int tid = threadIdx.x;
  const int b = blockIdx.y, blk = blockIdx.x;
  const int w = tid >> 6, l = tid & 63;
  const int lr = l & 15, g = l >> 4;
  const int h = w >> 1, qb = (w & 1) * 2;     // conv: half h, quarters qb, qb+1
  const int n0 = blk * 128;
  const float* xb = x + (size_t)b * 64 * HW + (size_t)h * NPOS;

  // conv B-fragments (weights, hi/lo): [ch-tile][kstep]
  short8 wbh[4][2], wbl[4][2];
  #pragma unroll
  for (int cht = 0; cht < 4; ++cht)
    #pragma unroll
    for (int ks = 0; ks < 2; ++ks) {
      const size_t off = (size_t)(cht * 16 + lr) * 64 + ks * 32 + g * 8;
      wbh[cht][ks] = *(const short8*)(Whi + off);
      wbl[cht][ks] = *(const short8*)(Wlo + off);
    }

  f32x4 aacc[4] = {{0.f,0.f,0.f,0.f},{0.f,0.f,0.f,0.f},{0.f,0.f,0.f,0.f},{0.f,0.f,0.f,0.f}};
  float ssp = 0.f, ssg = 0.f;

  // A-fragment loads: lane (lr,g), element e -> channel (e>>3)*32+g*8+(e&7),
  // pos = base + lr (16 consecutive cols per 16-lane group: coalesced)
  float xvA[16], xvB[16];
  #pragma unroll
  for (int e = 0; e < 16; ++e) {
    const size_t co = (size_t)((e >> 3) * 32 + g * 8 + (e & 7)) * HW;
    xvA[e] = xb[co + n0 + (qb + 0) * 16 + lr];
    xvB[e] = xb[co + n0 + (qb + 1) * 16 + lr];
  }

  for (int t = 0; t < 2; ++t) {
    // two pos-tiles: convert, conv-MFMA, exp, E write
    #pragma unroll
    for (int j = 0; j < 2; ++j) {
      const float* xv = j ? xvB : xvA;
      short8 ah[2];
      #pragma unroll
      for (int ks = 0; ks < 2; ++ks)
        #pragma unroll
        for (int e = 0; e < 8; ++e)
          ah[ks][e] = (short)f2bf(xv[ks * 8 + e]);
      f32x4 cacc[4] = {{0.f,0.f,0.f,0.f},{0.f,0.f,0.f,0.f},{0.f,0.f,0.f,0.f},{0.f,0.f,0.f,0.f}};
      #pragma unroll
      for (int cht = 0; cht < 4; ++cht)
        #pragma unroll
        for (int ks = 0; ks < 2; ++ks) {
          cacc[cht] = __builtin_amdgcn_mfma_f32_16x16x32_bf16(ah[ks], wbh[cht][ks], cacc[cht], 0, 0, 0);
          cacc[cht] = __builtin_amdgcn_mfma_f32_16x16x32_bf16(ah[ks], wbl[cht][ks], cacc[cht], 0, 0, 0);
        }
      // exp + E write: lane holds D[pos=g*4+r][ch=lr] -> row f(ch), 4 consec n
      #pragma unroll
      for (int cht = 0; cht < 4; ++cht) {
        const float e0 = __expf(cacc[cht][0]);
        const float e1 = __expf(cacc[cht][1]);
        const float e2 = __expf(cacc[cht][2]);
        const float e3 = __expf(cacc[cht][3]);
        if (cht < 2) ssp += (e0 + e1) + (e2 + e3);
        else         ssg += (e0 + e1) + (e2 + e3);
        const int row = ((cht >= 2) ? 64 : 0) + 2 * ((cht & 1) * 16 + lr) + h;
        uint2 pk;
        pk.x = (unsigned)f2bf(e0) | ((unsigned)f2bf(e1) << 16);
        pk.y = (unsigned)f2bf(e2) | ((unsigned)f2bf(e3) << 16);
        *(uint2*)&E[row * 68 + (qb + j) * 16 + g * 4] = pk;
      }
    }
    // prefetch next subtile BEFORE the barrier (drain overlaps sibling-wait)
    if (t < 1) {
      const int nn = n0 + 64;
      #pragma unroll
      for (int e = 0; e < 16; ++e) {
        const size_t co = (size_t)((e >> 3) * 32 + g * 8 + (e & 7)) * HW;
        xvA[e] = xb[co + nn + (qb + 0) * 16 + lr];
        xvB[e] = xb[co + nn + (qb + 1) * 16 + lr];
      }
    }
    __syncthreads();   // E complete

    // att: wave owns row-block w vs col-blocks 0..3, K=64 (2 ksteps)
    #pragma unroll
    for (int ks = 0; ks < 2; ++ks) {
      const short8 ag = ld_e16(&E[(64 + w * 16 + lr) * 68 + ks * 32 + g * 8]);
      #pragma unroll
      for (int j = 0; j < 4; ++j) {
        const short8 bp = ld_e16(&E[(j * 16 + lr) * 68 + ks * 32 + g * 8]);
        aacc[j] = __builtin_amdgcn_mfma_f32_16x16x32_bf16(ag, bp, aacc[j], 0, 0, 0);
      }
    }
    if (t < 1) __syncthreads();   // att reads done before next E write
  }

  // flush att partials: lane holds att[w*16+g*4+r][j*16+lr]
  float* ap = attP + (size_t)(b * 256 + blk) * 4096;
  #pragma unroll
  for (int j = 0; j < 4; ++j)
    #pragma unroll
    for (int r = 0; r < 4; ++r)
      ap[(w * 16 + g * 4 + r) * 64 + j * 16 + lr] = aacc[j][r];

  // softmax denominators -> per-block slot (NO atomics)
  #pragma unroll
  for (int off = 32; off > 0; off >>= 1) {
    ssp += __shfl_down(ssp, off);
    ssg += __shfl_down(ssg, off);
  }
  if (l == 0) rbuf[w] = make_float2(ssp, ssg);
  __syncthreads();
  if (tid == 0) {
    float a = 0.f, c = 0.f;
    #pragma unroll
    for (int i = 0; i < 4; ++i) { a += rbuf[i].x; c += rbuf[i].y; }
    spart[b * 256 + blk] = make_float2(a, c);
  }
}

// ---------------------------------------------------------------------------
// k3a: partial-reduce att partials 256 -> 8 per batch. Grid (64).
// ---------------------------------------------------------------------------
__global__ __launch_bounds__(256) void k3a_reduce(
    const float* __restrict__ attP, float* __restrict__ attQ)
{
  const int b = blockIdx.x >> 3, part = blockIdx.x & 7;
  const float* p = attP + (size_t)(b * 256 + part * 32) * 4096;
  float* q = attQ + (size_t)(b * 8 + part) * 4096;
  for (int e = threadIdx.x; e < 4096; e += 256) {
    float s0 = 0.f, s1 = 0.f, s2 = 0.f, s3 = 0.f;
    #pragma unroll
    for (int k = 0; k < 32; k += 4) {
      s0 += p[(size_t)k * 4096 + e];
      s1 += p[(size_t)(k + 1) * 4096 + e];
      s2 += p[(size_t)(k + 2) * 4096 + e];
      s3 += p[(size_t)(k + 3) * 4096 + e];
    }
    q[e] = (s0 + s1) + (s2 + s3);
  }
}

// ---------------------------------------------------------------------------
// k3b: reduce spart (256 float2/batch) -> scale; final att reduce; N mats.
// ---------------------------------------------------------------------------
__global__ __launch_bounds__(1024) void k3b_nmat(
    const float* __restrict__ attQ, const float2* __restrict__ spart,
    const float* __restrict__ wm, const float* __restrict__ wtheta,
    unsigned short* __restrict__ Nhi, unsigned short* __restrict__ Nlo)
{
  __shared__ float att_s[4096];
  __shared__ float Mp[2][64][64];
  __shared__ float wms[64][32];
  __shared__ float wts[32][64];
  __shared__ float sP[256], sG[256];
  const int tid = threadIdx.x;
  const int b = blockIdx.x;

  if (tid < 512) {
    if (tid < 256) {
      const float2 v = spart[b * 256 + tid];
      sP[tid] = v.x; sG[tid] = v.y;
      for (int k = tid; k < 2048; k += 256) wms[k >> 5][k & 31] = wm[k];
    } else {
      for (int k = tid - 256; k < 2048; k += 256) wts[k >> 6][k & 63] = wtheta[k];
    }
  }
  for (int e = tid; e < 4096; e += 1024) {
    const float* p = attQ + (size_t)b * 8 * 4096 + e;
    float s = 0.f;
    #pragma unroll
    for (int q = 0; q < 8; ++q) s += p[(size_t)q * 4096];
    att_s[e] = s;
  }
  __syncthreads();
  #pragma unroll
  for (int s = 128; s > 0; s >>= 1) {
    if (tid < s) { sP[tid] += sP[tid + s]; sG[tid] += sG[tid + s]; }
    __syncthreads();
  }
  for (int idx = tid; idx < 8192; idx += 1024) {
    const int h = idx >> 12, o = (idx >> 6) & 63, d = idx & 63;
    float s = 0.f;
    #pragma unroll
    for (int i = 0; i < 32; ++i)
      s = __builtin_fmaf(wms[o][i], att_s[(2 * i + h) * 64 + d], s);
    Mp[h][o][d] = s;
  }
  __syncthreads();
  const float scale = 1.f / (sP[0] * sG[0]);
  for (int idx = tid; idx < 16384; idx += 1024) {
    const int oo = idx >> 7, cc = idx & 127;
    const int h = oo >> 6, o = oo & 63, e = cc >> 6, c = cc & 63;
    float s = 0.f;
    #pragma unroll
    for (int j = 0; j < 32; ++j)
      s = __builtin_fmaf(Mp[h][o][2 * j + e], wts[j][c], s);
    s *= scale;
    const unsigned short hi = f2bf(s);
    Nhi[(size_t)b * 16384 + idx] = hi;
    Nlo[(size_t)b * 16384 + idx] = f2bf(s - bf2f(hi));
  }
}

// ---------------------------------------------------------------------------
// k5: out[b][o][h*NPOS+n] = sum_cc N[b][h*64+o][cc] * x[b][cc&63][(cc>>6)*NPOS+n]
// A = x [n][cc], B = N rows (oo) -> lane stores float4 of consecutive n.
// ---------------------------------------------------------------------------
__global__ __launch_bounds__(512) void k5_out(
    const float* __restrict__ x, const unsigned short* __restrict__ Nhi,
    const unsigned short* __restrict__ Nlo, float* __restrict__ out)
{
  __shared__ unsigned short Xh[64 * 128];   // [n][cc] bf16, cc ^ (slot4(n)<<3)
  const int tid = threadIdx.x;
  const int b = blockIdx.y, n0 = blockIdx.x * 64;
  const int w = tid >> 6, l = tid & 63;
  const int lr = l & 15, g = l >> 4;

  short8 bh[4], bl[4];
  #pragma unroll
  for (int ks = 0; ks < 4; ++ks) {
    const size_t off = (size_t)b * 16384 + (size_t)(w * 16 + lr) * 128 + ks * 32 + g * 8;
    bh[ks] = *(const short8*)(Nhi + off);
    bl[ks] = *(const short8*)(Nlo + off);
  }

  {
    const int ccb = w * 16;
    const int c0 = ccb & 63, e0 = ccb >> 6;
    const float* xp = x + (size_t)b * 64 * HW + (size_t)c0 * HW
                    + (size_t)e0 * NPOS + n0 + l;
    float v[16];
    #pragma unroll
    for (int i = 0; i < 16; ++i) v[i] = xp[(size_t)i * HW];
    short8 pa, pb;
    #pragma unroll
    for (int i = 0; i < 8; ++i) {
      pa[i] = (short)f2bf(v[i]);
      pb[i] = (short)f2bf(v[8 + i]);
    }
    const int s8 = slot4(l) << 3;
    *(short8*)&Xh[l * 128 + (ccb ^ s8)] = pa;
    *(short8*)&Xh[l * 128 + ((ccb + 8) ^ s8)] = pb;
  }
  __syncthreads();

  const int oo = w * 16 + lr;
  float* op = out + (size_t)b * 64 * HW + (size_t)(oo & 63) * HW
            + (size_t)(oo >> 6) * NPOS + n0 + g * 4;

  #pragma unroll
  for (int ct4 = 0; ct4 < 4; ++ct4) {
    f32x4 acc = {0.f, 0.f, 0.f, 0.f};
    const int arow = ct4 * 16 + lr;
    const int sw = slot4(arow) << 3;
    #pragma unroll
    for (int ks = 0; ks < 4; ++ks) {
      const short8 av = *(const short8*)&Xh[arow * 128 + ((ks * 32 + g * 8) ^ sw)];
      acc = __builtin_amdgcn_mfma_f32_16x16x32_bf16(av, bh[ks], acc, 0, 0, 0);
      acc = __builtin_amdgcn_mfma_f32_16x16x32_bf16(av, bl[ks], acc, 0, 0, 0);
    }
    *(float4*)(op + ct4 * 16) = *(float4*)&acc;
  }
}

// ---------------------------------------------------------------------------
extern "C" void kernel_launch(void* const* d_in, const int* in_sizes, int n_in,
                              void* d_out, int out_size, void* d_ws, size_t ws_size,
                              hipStream_t stream)
{
  const float* x      = (const float*)d_in[0];
  const float* wphi   = (const float*)d_in[1];
  const float* wtheta = (const float*)d_in[2];
  const float* wg     = (const float*)d_in[3];
  const float* wm     = (const float*)d_in[4];
  float* out = (float*)d_out;

  char* ws = (char*)d_ws;
  float* attP         = (float*)ws;                                 // 33,554,432 B
  unsigned short* Whi = (unsigned short*)(ws + 33554432);           //      8,192 B
  unsigned short* Wlo = (unsigned short*)(ws + 33562624);           //      8,192 B
  unsigned short* Nhi = (unsigned short*)(ws + 33570816);           //    262,144 B
  unsigned short* Nlo = (unsigned short*)(ws + 33832960);           //    262,144 B
  float2* spart       = (float2*)(ws + 34095104);                   //     16,384 B
  float* attQ         = (float*)(ws + 34111488);                    //  1,048,576 B

  k0_prep<<<dim3(16), 256, 0, stream>>>(wphi, wg, Whi, Wlo);
  k1_att<<<dim3(256, 8), 256, 0, stream>>>(x, Whi, Wlo, attP, spart);
  k3a_reduce<<<dim3(64), 256, 0, stream>>>(attP, attQ);
  k3b_nmat<<<dim3(8), 1024, 0, stream>>>(attQ, spart, wm, wtheta, Nhi, Nlo);
  k5_out<<<dim3(512, 8), 512, 0, stream>>>(x, Nhi, Nlo, out);
}

// Round 14
// 118.341 us; speedup vs baseline: 1.1259x; 1.1259x over previous
//
#include <hip/hip_runtime.h>

typedef __attribute__((ext_vector_type(8))) short short8;
typedef __attribute__((ext_vector_type(4))) float f32x4;
typedef __attribute__((ext_vector_type(4))) unsigned int uint4v;

#define HW 65536
#define NPOS 32768

__device__ __forceinline__ unsigned short f2bf(float f) {
  unsigned u = __builtin_bit_cast(unsigned, f);
  u += 0x7fffu + ((u >> 16) & 1u);
  return (unsigned short)(u >> 16);
}
__device__ __forceinline__ float bf2f(unsigned short h) {
  unsigned u = (unsigned)h << 16;
  return __builtin_bit_cast(float, u);
}
__device__ __forceinline__ int slot4(int r) { return (r ^ (r >> 2)) & 15; }
// 16B fragment from 8B-aligned LDS (row stride 136B) as two b64 reads
__device__ __forceinline__ short8 ld_e16(const unsigned short* p) {
  const uint2 a = *(const uint2*)p;
  const uint2 b = *(const uint2*)(p + 4);
  uint4v u = {a.x, a.y, b.x, b.y};
  return __builtin_bit_cast(short8, u);
}

// ---------------------------------------------------------------------------
// k0: split conv weights to bf16 hi/lo; rows 0-31 = phi, 32-63 = g.
// ---------------------------------------------------------------------------
__global__ __launch_bounds__(256) void k0_prep(
    const float* __restrict__ wphi, const float* __restrict__ wg,
    unsigned short* __restrict__ Whi, unsigned short* __restrict__ Wlo)
{
  const int idx = blockIdx.x * 256 + threadIdx.x;  // 4096 total
  const int u = idx >> 6, c = idx & 63;
  const float w = (u < 32) ? wphi[u * 64 + c] : wg[(u - 32) * 64 + c];
  const unsigned short h = f2bf(w);
  Whi[idx] = h;
  Wlo[idx] = f2bf(w - bf2f(h));
}

// ---------------------------------------------------------------------------
// k1: FUSED conv + exp + att, atomic-free (R12 proven config: 125.2 µs).
// Grid (128, 8). Block = 4 waves / 256 thr, owns 256 view-cols = 4 subtiles.
// E double-buffered in LDS (2 x 17.4 KB), ONE barrier/subtile; prefetch of
// the next subtile's x issues before the barrier. Per-block spart slot.
// ---------------------------------------------------------------------------
__global__ __launch_bounds__(256) void k1_att(
    const float* __restrict__ x, const unsigned short* __restrict__ Whi,
    const unsigned short* __restrict__ Wlo, float* __restrict__ attP,
    float2* __restrict__ spart)
{
  __shared__ unsigned short E[2][128 * 68];   // [buf][row][68]; rows 0-63 Ep, 64-127 Eg
  __shared__ float2 rbuf[4];

  const int tid = threadIdx.x;
  const int b = blockIdx.y, blk = blockIdx.x;
  const int w = tid >> 6, l = tid & 63;
  const int lr = l & 15, g = l >> 4;
  const int h = w >> 1, qb = (w & 1) * 2;     // conv: half h, quarters qb, qb+1
  const int n0 = blk * 256;
  const float* xb = x + (size_t)b * 64 * HW + (size_t)h * NPOS;

  // conv B-fragments (weights, hi/lo): [ch-tile][kstep]
  short8 wbh[4][2], wbl[4][2];
  #pragma unroll
  for (int cht = 0; cht < 4; ++cht)
    #pragma unroll
    for (int ks = 0; ks < 2; ++ks) {
      const size_t off = (size_t)(cht * 16 + lr) * 64 + ks * 32 + g * 8;
      wbh[cht][ks] = *(const short8*)(Whi + off);
      wbl[cht][ks] = *(const short8*)(Wlo + off);
    }

  f32x4 aacc[4] = {{0.f,0.f,0.f,0.f},{0.f,0.f,0.f,0.f},{0.f,0.f,0.f,0.f},{0.f,0.f,0.f,0.f}};
  float ssp = 0.f, ssg = 0.f;

  // A-fragment loads: lane (lr,g), element e -> channel (e>>3)*32+g*8+(e&7),
  // pos = base + lr (16 consecutive cols per 16-lane group: coalesced)
  float xvA[16], xvB[16];
  #pragma unroll
  for (int e = 0; e < 16; ++e) {
    const size_t co = (size_t)((e >> 3) * 32 + g * 8 + (e & 7)) * HW;
    xvA[e] = xb[co + n0 + (qb + 0) * 16 + lr];
    xvB[e] = xb[co + n0 + (qb + 1) * 16 + lr];
  }

  for (int t = 0; t < 4; ++t) {
    const int buf = t & 1;
    // two pos-tiles: convert, conv-MFMA, exp, E write
    #pragma unroll
    for (int j = 0; j < 2; ++j) {
      const float* xv = j ? xvB : xvA;
      short8 ah[2];
      #pragma unroll
      for (int ks = 0; ks < 2; ++ks)
        #pragma unroll
        for (int e = 0; e < 8; ++e)
          ah[ks][e] = (short)f2bf(xv[ks * 8 + e]);
      f32x4 cacc[4] = {{0.f,0.f,0.f,0.f},{0.f,0.f,0.f,0.f},{0.f,0.f,0.f,0.f},{0.f,0.f,0.f,0.f}};
      #pragma unroll
      for (int cht = 0; cht < 4; ++cht)
        #pragma unroll
        for (int ks = 0; ks < 2; ++ks) {
          cacc[cht] = __builtin_amdgcn_mfma_f32_16x16x32_bf16(ah[ks], wbh[cht][ks], cacc[cht], 0, 0, 0);
          cacc[cht] = __builtin_amdgcn_mfma_f32_16x16x32_bf16(ah[ks], wbl[cht][ks], cacc[cht], 0, 0, 0);
        }
      // exp + E[buf] write: lane holds D[pos=g*4+r][ch=lr] -> row f(ch), 4 consec n
      #pragma unroll
      for (int cht = 0; cht < 4; ++cht) {
        const float e0 = __expf(cacc[cht][0]);
        const float e1 = __expf(cacc[cht][1]);
        const float e2 = __expf(cacc[cht][2]);
        const float e3 = __expf(cacc[cht][3]);
        if (cht < 2) ssp += (e0 + e1) + (e2 + e3);
        else         ssg += (e0 + e1) + (e2 + e3);
        const int row = ((cht >= 2) ? 64 : 0) + 2 * ((cht & 1) * 16 + lr) + h;
        uint2 pk;
        pk.x = (unsigned)f2bf(e0) | ((unsigned)f2bf(e1) << 16);
        pk.y = (unsigned)f2bf(e2) | ((unsigned)f2bf(e3) << 16);
        *(uint2*)&E[buf][row * 68 + (qb + j) * 16 + g * 4] = pk;
      }
    }
    // prefetch next subtile BEFORE the barrier (drain overlaps sibling-wait)
    if (t < 3) {
      const int nn = n0 + (t + 1) * 64;
      #pragma unroll
      for (int e = 0; e < 16; ++e) {
        const size_t co = (size_t)((e >> 3) * 32 + g * 8 + (e & 7)) * HW;
        xvA[e] = xb[co + nn + (qb + 0) * 16 + lr];
        xvB[e] = xb[co + nn + (qb + 1) * 16 + lr];
      }
    }
    __syncthreads();   // E[buf] complete; E[buf^1] readers (t-1) done

    // att: wave owns row-block w vs col-blocks 0..3, K=64 (2 ksteps)
    #pragma unroll
    for (int ks = 0; ks < 2; ++ks) {
      const short8 ag = ld_e16(&E[buf][(64 + w * 16 + lr) * 68 + ks * 32 + g * 8]);
      #pragma unroll
      for (int j = 0; j < 4; ++j) {
        const short8 bp = ld_e16(&E[buf][(j * 16 + lr) * 68 + ks * 32 + g * 8]);
        aacc[j] = __builtin_amdgcn_mfma_f32_16x16x32_bf16(ag, bp, aacc[j], 0, 0, 0);
      }
    }
  }

  // flush att partials: lane holds att[w*16+g*4+r][j*16+lr]
  float* ap = attP + (size_t)(b * 128 + blk) * 4096;
  #pragma unroll
  for (int j = 0; j < 4; ++j)
    #pragma unroll
    for (int r = 0; r < 4; ++r)
      ap[(w * 16 + g * 4 + r) * 64 + j * 16 + lr] = aacc[j][r];

  // softmax denominators -> per-block slot (NO atomics)
  #pragma unroll
  for (int off = 32; off > 0; off >>= 1) {
    ssp += __shfl_down(ssp, off);
    ssg += __shfl_down(ssg, off);
  }
  if (l == 0) rbuf[w] = make_float2(ssp, ssg);
  __syncthreads();
  if (tid == 0) {
    float a = 0.f, c = 0.f;
    #pragma unroll
    for (int i = 0; i < 4; ++i) { a += rbuf[i].x; c += rbuf[i].y; }
    spart[b * 128 + blk] = make_float2(a, c);
  }
}

// ---------------------------------------------------------------------------
// k3a: partial-reduce att partials 128 -> 8 per batch, e-split 4x for chip-
// wide spread. Grid (256): b = blk>>5, part = (blk>>2)&7, es = blk&3.
// Each block reduces 16 partials over a 1024-element e-range (64 KB read).
// ---------------------------------------------------------------------------
__global__ __launch_bounds__(256) void k3a_reduce(
    const float* __restrict__ attP, float* __restrict__ attQ)
{
  const int b = blockIdx.x >> 5, part = (blockIdx.x >> 2) & 7, es = blockIdx.x & 3;
  const float* p = attP + (size_t)(b * 128 + part * 16) * 4096 + es * 1024;
  float* q = attQ + (size_t)(b * 8 + part) * 4096 + es * 1024;
  for (int e = threadIdx.x; e < 1024; e += 256) {
    float s0 = 0.f, s1 = 0.f, s2 = 0.f, s3 = 0.f;
    #pragma unroll
    for (int k = 0; k < 16; k += 4) {
      s0 += p[(size_t)k * 4096 + e];
      s1 += p[(size_t)(k + 1) * 4096 + e];
      s2 += p[(size_t)(k + 2) * 4096 + e];
      s3 += p[(size_t)(k + 3) * 4096 + e];
    }
    q[e] = (s0 + s1) + (s2 + s3);
  }
}

// ---------------------------------------------------------------------------
// k3b: reduce spart (128 float2/batch) -> scale; final att reduce; N mats.
// ---------------------------------------------------------------------------
__global__ __launch_bounds__(1024) void k3b_nmat(
    const float* __restrict__ attQ, const float2* __restrict__ spart,
    const float* __restrict__ wm, const float* __restrict__ wtheta,
    unsigned short* __restrict__ Nhi, unsigned short* __restrict__ Nlo)
{
  __shared__ float att_s[4096];
  __shared__ float Mp[2][64][64];
  __shared__ float wms[64][32];
  __shared__ float wts[32][64];
  __shared__ float sP[128], sG[128];
  const int tid = threadIdx.x;
  const int b = blockIdx.x;

  if (tid < 512) {
    if (tid < 128) {
      const float2 v = spart[b * 128 + tid];
      sP[tid] = v.x; sG[tid] = v.y;
    }
    if (tid < 256) { for (int k = tid; k < 2048; k += 256) wms[k >> 5][k & 31] = wm[k]; }
    else           { for (int k = tid - 256; k < 2048; k += 256) wts[k >> 6][k & 63] = wtheta[k]; }
  }
  for (int e = tid; e < 4096; e += 1024) {
    const float* p = attQ + (size_t)b * 8 * 4096 + e;
    float s = 0.f;
    #pragma unroll
    for (int q = 0; q < 8; ++q) s += p[(size_t)q * 4096];
    att_s[e] = s;
  }
  __syncthreads();
  #pragma unroll
  for (int s = 64; s > 0; s >>= 1) {
    if (tid < s) { sP[tid] += sP[tid + s]; sG[tid] += sG[tid + s]; }
    __syncthreads();
  }
  for (int idx = tid; idx < 8192; idx += 1024) {
    const int h = idx >> 12, o = (idx >> 6) & 63, d = idx & 63;
    float s = 0.f;
    #pragma unroll
    for (int i = 0; i < 32; ++i)
      s = __builtin_fmaf(wms[o][i], att_s[(2 * i + h) * 64 + d], s);
    Mp[h][o][d] = s;
  }
  __syncthreads();
  const float scale = 1.f / (sP[0] * sG[0]);
  for (int idx = tid; idx < 16384; idx += 1024) {
    const int oo = idx >> 7, cc = idx & 127;
    const int h = oo >> 6, o = oo & 63, e = cc >> 6, c = cc & 63;
    float s = 0.f;
    #pragma unroll
    for (int j = 0; j < 32; ++j)
      s = __builtin_fmaf(Mp[h][o][2 * j + e], wts[j][c], s);
    s *= scale;
    const unsigned short hi = f2bf(s);
    Nhi[(size_t)b * 16384 + idx] = hi;
    Nlo[(size_t)b * 16384 + idx] = f2bf(s - bf2f(hi));
  }
}

// ---------------------------------------------------------------------------
// k5: out[b][o][h*NPOS+n] = sum_cc N[b][h*64+o][cc] * x[b][cc&63][(cc>>6)*NPOS+n]
// A = x [n][cc], B = N rows (oo) -> lane stores float4 of consecutive n.
// ---------------------------------------------------------------------------
__global__ __launch_bounds__(512) void k5_out(
    const float* __restrict__ x, const unsigned short* __restrict__ Nhi,
    const unsigned short* __restrict__ Nlo, float* __restrict__ out)
{
  __shared__ unsigned short Xh[64 * 128];   // [n][cc] bf16, cc ^ (slot4(n)<<3)
  const int tid = threadIdx.x;
  const int b = blockIdx.y, n0 = blockIdx.x * 64;
  const int w = tid >> 6, l = tid & 63;
  const int lr = l & 15, g = l >> 4;

  short8 bh[4], bl[4];
  #pragma unroll
  for (int ks = 0; ks < 4; ++ks) {
    const size_t off = (size_t)b * 16384 + (size_t)(w * 16 + lr) * 128 + ks * 32 + g * 8;
    bh[ks] = *(const short8*)(Nhi + off);
    bl[ks] = *(const short8*)(Nlo + off);
  }

  {
    const int ccb = w * 16;
    const int c0 = ccb & 63, e0 = ccb >> 6;
    const float* xp = x + (size_t)b * 64 * HW + (size_t)c0 * HW
                    + (size_t)e0 * NPOS + n0 + l;
    float v[16];
    #pragma unroll
    for (int i = 0; i < 16; ++i) v[i] = xp[(size_t)i * HW];
    short8 pa, pb;
    #pragma unroll
    for (int i = 0; i < 8; ++i) {
      pa[i] = (short)f2bf(v[i]);
      pb[i] = (short)f2bf(v[8 + i]);
    }
    const int s8 = slot4(l) << 3;
    *(short8*)&Xh[l * 128 + (ccb ^ s8)] = pa;
    *(short8*)&Xh[l * 128 + ((ccb + 8) ^ s8)] = pb;
  }
  __syncthreads();

  const int oo = w * 16 + lr;
  float* op = out + (size_t)b * 64 * HW + (size_t)(oo & 63) * HW
            + (size_t)(oo >> 6) * NPOS + n0 + g * 4;

  #pragma unroll
  for (int ct4 = 0; ct4 < 4; ++ct4) {
    f32x4 acc = {0.f, 0.f, 0.f, 0.f};
    const int arow = ct4 * 16 + lr;
    const int sw = slot4(arow) << 3;
    #pragma unroll
    for (int ks = 0; ks < 4; ++ks) {
      const short8 av = *(const short8*)&Xh[arow * 128 + ((ks * 32 + g * 8) ^ sw)];
      acc = __builtin_amdgcn_mfma_f32_16x16x32_bf16(av, bh[ks], acc, 0, 0, 0);
      acc = __builtin_amdgcn_mfma_f32_16x16x32_bf16(av, bl[ks], acc, 0, 0, 0);
    }
    *(float4*)(op + ct4 * 16) = *(float4*)&acc;
  }
}

// ---------------------------------------------------------------------------
extern "C" void kernel_launch(void* const* d_in, const int* in_sizes, int n_in,
                              void* d_out, int out_size, void* d_ws, size_t ws_size,
                              hipStream_t stream)
{
  const float* x      = (const float*)d_in[0];
  const float* wphi   = (const float*)d_in[1];
  const float* wtheta = (const float*)d_in[2];
  const float* wg     = (const float*)d_in[3];
  const float* wm     = (const float*)d_in[4];
  float* out = (float*)d_out;

  char* ws = (char*)d_ws;
  float* attP         = (float*)ws;                                 // 16,777,216 B
  unsigned short* Whi = (unsigned short*)(ws + 16777216);           //      8,192 B
  unsigned short* Wlo = (unsigned short*)(ws + 16785408);           //      8,192 B
  unsigned short* Nhi = (unsigned short*)(ws + 16793600);           //    262,144 B
  unsigned short* Nlo = (unsigned short*)(ws + 17055744);           //    262,144 B
  float2* spart       = (float2*)(ws + 17317888);                   //      8,192 B
  float* attQ         = (float*)(ws + 17326080);                    //  1,048,576 B

  k0_prep<<<dim3(16), 256, 0, stream>>>(wphi, wg, Whi, Wlo);
  k1_att<<<dim3(128, 8), 256, 0, stream>>>(x, Whi, Wlo, attP, spart);
  k3a_reduce<<<dim3(256), 256, 0, stream>>>(attP, attQ);
  k3b_nmat<<<dim3(8), 1024, 0, stream>>>(attQ, spart, wm, wtheta, Nhi, Nlo);
  k5_out<<<dim3(512, 8), 512, 0, stream>>>(x, Nhi, Nlo, out);
}

// Round 15
// 109.468 us; speedup vs baseline: 1.2172x; 1.0811x over previous
//
#include <hip/hip_runtime.h>

typedef __attribute__((ext_vector_type(8))) short short8;
typedef __attribute__((ext_vector_type(4))) float f32x4;
typedef __attribute__((ext_vector_type(4))) unsigned int uint4v;

#define HW 65536
#define NPOS 32768

__device__ __forceinline__ unsigned short f2bf(float f) {
  unsigned u = __builtin_bit_cast(unsigned, f);
  u += 0x7fffu + ((u >> 16) & 1u);
  return (unsigned short)(u >> 16);
}
__device__ __forceinline__ float bf2f(unsigned short h) {
  unsigned u = (unsigned)h << 16;
  return __builtin_bit_cast(float, u);
}
__device__ __forceinline__ int slot4(int r) { return (r ^ (r >> 2)) & 15; }
// 16B fragment from 8B-aligned LDS (row stride 136B) as two b64 reads
__device__ __forceinline__ short8 ld_e16(const unsigned short* p) {
  const uint2 a = *(const uint2*)p;
  const uint2 b = *(const uint2*)(p + 4);
  uint4v u = {a.x, a.y, b.x, b.y};
  return __builtin_bit_cast(short8, u);
}

// ---------------------------------------------------------------------------
// k0: split conv weights to bf16 hi/lo; rows 0-31 = phi, 32-63 = g.
// ---------------------------------------------------------------------------
__global__ __launch_bounds__(256) void k0_prep(
    const float* __restrict__ wphi, const float* __restrict__ wg,
    unsigned short* __restrict__ Whi, unsigned short* __restrict__ Wlo)
{
  const int idx = blockIdx.x * 256 + threadIdx.x;  // 4096 total
  const int u = idx >> 6, c = idx & 63;
  const float w = (u < 32) ? wphi[u * 64 + c] : wg[(u - 32) * 64 + c];
  const unsigned short h = f2bf(w);
  Whi[idx] = h;
  Wlo[idx] = f2bf(w - bf2f(h));
}

// ---------------------------------------------------------------------------
// k1: FUSED conv + exp + att, atomic-free (R12/R14 proven config).
// Grid (128, 8). Block = 4 waves / 256 thr, owns 256 view-cols = 4 subtiles.
// E double-buffered in LDS (2 x 17.4 KB), ONE barrier/subtile; prefetch of
// the next subtile's x issues before the barrier. attP partials now bf16
// (error contribution ~1e-10, halves flush traffic). Per-block spart slot.
// ---------------------------------------------------------------------------
__global__ __launch_bounds__(256) void k1_att(
    const float* __restrict__ x, const unsigned short* __restrict__ Whi,
    const unsigned short* __restrict__ Wlo, unsigned short* __restrict__ attP,
    float2* __restrict__ spart)
{
  __shared__ unsigned short E[2][128 * 68];   // [buf][row][68]; rows 0-63 Ep, 64-127 Eg
  __shared__ float2 rbuf[4];

  const int tid = threadIdx.x;
  const int b = blockIdx.y, blk = blockIdx.x;
  const int w = tid >> 6, l = tid & 63;
  const int lr = l & 15, g = l >> 4;
  const int h = w >> 1, qb = (w & 1) * 2;     // conv: half h, quarters qb, qb+1
  const int n0 = blk * 256;
  const float* xb = x + (size_t)b * 64 * HW + (size_t)h * NPOS;

  // conv B-fragments (weights, hi/lo): [ch-tile][kstep]
  short8 wbh[4][2], wbl[4][2];
  #pragma unroll
  for (int cht = 0; cht < 4; ++cht)
    #pragma unroll
    for (int ks = 0; ks < 2; ++ks) {
      const size_t off = (size_t)(cht * 16 + lr) * 64 + ks * 32 + g * 8;
      wbh[cht][ks] = *(const short8*)(Whi + off);
      wbl[cht][ks] = *(const short8*)(Wlo + off);
    }

  f32x4 aacc[4] = {{0.f,0.f,0.f,0.f},{0.f,0.f,0.f,0.f},{0.f,0.f,0.f,0.f},{0.f,0.f,0.f,0.f}};
  float ssp = 0.f, ssg = 0.f;

  // A-fragment loads: lane (lr,g), element e -> channel (e>>3)*32+g*8+(e&7),
  // pos = base + lr (16 consecutive cols per 16-lane group: coalesced)
  float xvA[16], xvB[16];
  #pragma unroll
  for (int e = 0; e < 16; ++e) {
    const size_t co = (size_t)((e >> 3) * 32 + g * 8 + (e & 7)) * HW;
    xvA[e] = xb[co + n0 + (qb + 0) * 16 + lr];
    xvB[e] = xb[co + n0 + (qb + 1) * 16 + lr];
  }

  for (int t = 0; t < 4; ++t) {
    const int buf = t & 1;
    // two pos-tiles: convert, conv-MFMA, exp, E write
    #pragma unroll
    for (int j = 0; j < 2; ++j) {
      const float* xv = j ? xvB : xvA;
      short8 ah[2];
      #pragma unroll
      for (int ks = 0; ks < 2; ++ks)
        #pragma unroll
        for (int e = 0; e < 8; ++e)
          ah[ks][e] = (short)f2bf(xv[ks * 8 + e]);
      f32x4 cacc[4] = {{0.f,0.f,0.f,0.f},{0.f,0.f,0.f,0.f},{0.f,0.f,0.f,0.f},{0.f,0.f,0.f,0.f}};
      #pragma unroll
      for (int cht = 0; cht < 4; ++cht)
        #pragma unroll
        for (int ks = 0; ks < 2; ++ks) {
          cacc[cht] = __builtin_amdgcn_mfma_f32_16x16x32_bf16(ah[ks], wbh[cht][ks], cacc[cht], 0, 0, 0);
          cacc[cht] = __builtin_amdgcn_mfma_f32_16x16x32_bf16(ah[ks], wbl[cht][ks], cacc[cht], 0, 0, 0);
        }
      // exp + E[buf] write: lane holds D[pos=g*4+r][ch=lr] -> row f(ch), 4 consec n
      #pragma unroll
      for (int cht = 0; cht < 4; ++cht) {
        const float e0 = __expf(cacc[cht][0]);
        const float e1 = __expf(cacc[cht][1]);
        const float e2 = __expf(cacc[cht][2]);
        const float e3 = __expf(cacc[cht][3]);
        if (cht < 2) ssp += (e0 + e1) + (e2 + e3);
        else         ssg += (e0 + e1) + (e2 + e3);
        const int row = ((cht >= 2) ? 64 : 0) + 2 * ((cht & 1) * 16 + lr) + h;
        uint2 pk;
        pk.x = (unsigned)f2bf(e0) | ((unsigned)f2bf(e1) << 16);
        pk.y = (unsigned)f2bf(e2) | ((unsigned)f2bf(e3) << 16);
        *(uint2*)&E[buf][row * 68 + (qb + j) * 16 + g * 4] = pk;
      }
    }
    // prefetch next subtile BEFORE the barrier (drain overlaps sibling-wait)
    if (t < 3) {
      const int nn = n0 + (t + 1) * 64;
      #pragma unroll
      for (int e = 0; e < 16; ++e) {
        const size_t co = (size_t)((e >> 3) * 32 + g * 8 + (e & 7)) * HW;
        xvA[e] = xb[co + nn + (qb + 0) * 16 + lr];
        xvB[e] = xb[co + nn + (qb + 1) * 16 + lr];
      }
    }
    __syncthreads();   // E[buf] complete; E[buf^1] readers (t-1) done

    // att: wave owns row-block w vs col-blocks 0..3, K=64 (2 ksteps)
    #pragma unroll
    for (int ks = 0; ks < 2; ++ks) {
      const short8 ag = ld_e16(&E[buf][(64 + w * 16 + lr) * 68 + ks * 32 + g * 8]);
      #pragma unroll
      for (int j = 0; j < 4; ++j) {
        const short8 bp = ld_e16(&E[buf][(j * 16 + lr) * 68 + ks * 32 + g * 8]);
        aacc[j] = __builtin_amdgcn_mfma_f32_16x16x32_bf16(ag, bp, aacc[j], 0, 0, 0);
      }
    }
  }

  // flush att partials as bf16: lane holds att[w*16+g*4+r][j*16+lr]
  unsigned short* ap = attP + (size_t)(b * 128 + blk) * 4096;
  #pragma unroll
  for (int j = 0; j < 4; ++j)
    #pragma unroll
    for (int r = 0; r < 4; ++r)
      ap[(w * 16 + g * 4 + r) * 64 + j * 16 + lr] = f2bf(aacc[j][r]);

  // softmax denominators -> per-block slot (NO atomics)
  #pragma unroll
  for (int off = 32; off > 0; off >>= 1) {
    ssp += __shfl_down(ssp, off);
    ssg += __shfl_down(ssg, off);
  }
  if (l == 0) rbuf[w] = make_float2(ssp, ssg);
  __syncthreads();
  if (tid == 0) {
    float a = 0.f, c = 0.f;
    #pragma unroll
    for (int i = 0; i < 4; ++i) { a += rbuf[i].x; c += rbuf[i].y; }
    spart[b * 128 + blk] = make_float2(a, c);
  }
}

// ---------------------------------------------------------------------------
// k3a: partial-reduce bf16 att partials 128 -> 8 (fp32) per batch, e-split
// 4x for chip-wide spread. Grid (256): b = blk>>5, part = (blk>>2)&7, es = blk&3.
// ---------------------------------------------------------------------------
__global__ __launch_bounds__(256) void k3a_reduce(
    const unsigned short* __restrict__ attP, float* __restrict__ attQ)
{
  const int b = blockIdx.x >> 5, part = (blockIdx.x >> 2) & 7, es = blockIdx.x & 3;
  const unsigned short* p = attP + (size_t)(b * 128 + part * 16) * 4096 + es * 1024;
  float* q = attQ + (size_t)(b * 8 + part) * 4096 + es * 1024;
  for (int e = threadIdx.x; e < 1024; e += 256) {
    float s0 = 0.f, s1 = 0.f, s2 = 0.f, s3 = 0.f;
    #pragma unroll
    for (int k = 0; k < 16; k += 4) {
      s0 += bf2f(p[(size_t)k * 4096 + e]);
      s1 += bf2f(p[(size_t)(k + 1) * 4096 + e]);
      s2 += bf2f(p[(size_t)(k + 2) * 4096 + e]);
      s3 += bf2f(p[(size_t)(k + 3) * 4096 + e]);
    }
    q[e] = (s0 + s1) + (s2 + s3);
  }
}

// ---------------------------------------------------------------------------
// k3b: reduce spart (128 float2/batch) -> scale; final att reduce; N mats.
// ---------------------------------------------------------------------------
__global__ __launch_bounds__(1024) void k3b_nmat(
    const float* __restrict__ attQ, const float2* __restrict__ spart,
    const float* __restrict__ wm, const float* __restrict__ wtheta,
    unsigned short* __restrict__ Nhi, unsigned short* __restrict__ Nlo)
{
  __shared__ float att_s[4096];
  __shared__ float Mp[2][64][64];
  __shared__ float wms[64][32];
  __shared__ float wts[32][64];
  __shared__ float sP[128], sG[128];
  const int tid = threadIdx.x;
  const int b = blockIdx.x;

  if (tid < 512) {
    if (tid < 128) {
      const float2 v = spart[b * 128 + tid];
      sP[tid] = v.x; sG[tid] = v.y;
    }
    if (tid < 256) { for (int k = tid; k < 2048; k += 256) wms[k >> 5][k & 31] = wm[k]; }
    else           { for (int k = tid - 256; k < 2048; k += 256) wts[k >> 6][k & 63] = wtheta[k]; }
  }
  for (int e = tid; e < 4096; e += 1024) {
    const float* p = attQ + (size_t)b * 8 * 4096 + e;
    float s = 0.f;
    #pragma unroll
    for (int q = 0; q < 8; ++q) s += p[(size_t)q * 4096];
    att_s[e] = s;
  }
  __syncthreads();
  #pragma unroll
  for (int s = 64; s > 0; s >>= 1) {
    if (tid < s) { sP[tid] += sP[tid + s]; sG[tid] += sG[tid + s]; }
    __syncthreads();
  }
  for (int idx = tid; idx < 8192; idx += 1024) {
    const int h = idx >> 12, o = (idx >> 6) & 63, d = idx & 63;
    float s = 0.f;
    #pragma unroll
    for (int i = 0; i < 32; ++i)
      s = __builtin_fmaf(wms[o][i], att_s[(2 * i + h) * 64 + d], s);
    Mp[h][o][d] = s;
  }
  __syncthreads();
  const float scale = 1.f / (sP[0] * sG[0]);
  for (int idx = tid; idx < 16384; idx += 1024) {
    const int oo = idx >> 7, cc = idx & 127;
    const int h = oo >> 6, o = oo & 63, e = cc >> 6, c = cc & 63;
    float s = 0.f;
    #pragma unroll
    for (int j = 0; j < 32; ++j)
      s = __builtin_fmaf(Mp[h][o][2 * j + e], wts[j][c], s);
    s *= scale;
    const unsigned short hi = f2bf(s);
    Nhi[(size_t)b * 16384 + idx] = hi;
    Nlo[(size_t)b * 16384 + idx] = f2bf(s - bf2f(hi));
  }
}

// ---------------------------------------------------------------------------
// k5: out[b][o][h*NPOS+n] = sum_cc N[b][h*64+o][cc] * x[b][cc&63][(cc>>6)*NPOS+n]
// Grid (128, 8): block owns 256 n-cols = 4 tiles of 64; Xh double-buffered,
// ONE barrier/tile; N B-fragments loaded ONCE per block (traffic / 4).
// A = x [n][cc], B = N rows (oo) -> lane stores float4 of consecutive n.
// ---------------------------------------------------------------------------
__global__ __launch_bounds__(512) void k5_out(
    const float* __restrict__ x, const unsigned short* __restrict__ Nhi,
    const unsigned short* __restrict__ Nlo, float* __restrict__ out)
{
  __shared__ unsigned short Xh[2][64 * 128];   // [buf][n][cc], cc ^ (slot4(n)<<3)
  const int tid = threadIdx.x;
  const int b = blockIdx.y, n0 = blockIdx.x * 256;
  const int w = tid >> 6, l = tid & 63;
  const int lr = l & 15, g = l >> 4;

  // B-fragments: N rows oo = w*16 + lr, K=128 (4 ksteps), hi/lo — loaded once
  short8 bh[4], bl[4];
  #pragma unroll
  for (int ks = 0; ks < 4; ++ks) {
    const size_t off = (size_t)b * 16384 + (size_t)(w * 16 + lr) * 128 + ks * 32 + g * 8;
    bh[ks] = *(const short8*)(Nhi + off);
    bl[ks] = *(const short8*)(Nlo + off);
  }

  const int ccb = w * 16;
  const int c0 = ccb & 63, e0 = ccb >> 6;
  const float* xp = x + (size_t)b * 64 * HW + (size_t)c0 * HW
                  + (size_t)e0 * NPOS + n0 + l;
  const int s8 = slot4(l) << 3;
  const int oo = w * 16 + lr;
  float* op0 = out + (size_t)b * 64 * HW + (size_t)(oo & 63) * HW
             + (size_t)(oo >> 6) * NPOS + n0 + g * 4;

  // prologue: tile 0 loads (lane spans n: coalesced)
  float v[16];
  #pragma unroll
  for (int i = 0; i < 16; ++i) v[i] = xp[(size_t)i * HW];

  for (int t = 0; t < 4; ++t) {
    const int buf = t & 1;
    // pack + stage current tile
    {
      short8 pa, pb;
      #pragma unroll
      for (int i = 0; i < 8; ++i) {
        pa[i] = (short)f2bf(v[i]);
        pb[i] = (short)f2bf(v[8 + i]);
      }
      *(short8*)&Xh[buf][l * 128 + (ccb ^ s8)] = pa;
      *(short8*)&Xh[buf][l * 128 + ((ccb + 8) ^ s8)] = pb;
    }
    // prefetch next tile before the barrier
    if (t < 3) {
      #pragma unroll
      for (int i = 0; i < 16; ++i) v[i] = xp[(size_t)i * HW + (t + 1) * 64];
    }
    __syncthreads();   // Xh[buf] staged; Xh[buf^1] readers (t-1) done

    float* op = op0 + t * 64;
    #pragma unroll
    for (int ct4 = 0; ct4 < 4; ++ct4) {
      f32x4 acc = {0.f, 0.f, 0.f, 0.f};
      const int arow = ct4 * 16 + lr;
      const int sw = slot4(arow) << 3;
      #pragma unroll
      for (int ks = 0; ks < 4; ++ks) {
        const short8 av = *(const short8*)&Xh[buf][arow * 128 + ((ks * 32 + g * 8) ^ sw)];
        acc = __builtin_amdgcn_mfma_f32_16x16x32_bf16(av, bh[ks], acc, 0, 0, 0);
        acc = __builtin_amdgcn_mfma_f32_16x16x32_bf16(av, bl[ks], acc, 0, 0, 0);
      }
      *(float4*)(op + ct4 * 16) = *(float4*)&acc;
    }
  }
}

// ---------------------------------------------------------------------------
extern "C" void kernel_launch(void* const* d_in, const int* in_sizes, int n_in,
                              void* d_out, int out_size, void* d_ws, size_t ws_size,
                              hipStream_t stream)
{
  const float* x      = (const float*)d_in[0];
  const float* wphi   = (const float*)d_in[1];
  const float* wtheta = (const float*)d_in[2];
  const float* wg     = (const float*)d_in[3];
  const float* wm     = (const float*)d_in[4];
  float* out = (float*)d_out;

  char* ws = (char*)d_ws;
  unsigned short* attP = (unsigned short*)ws;                       //  8,388,608 B
  unsigned short* Whi = (unsigned short*)(ws + 8388608);            //      8,192 B
  unsigned short* Wlo = (unsigned short*)(ws + 8396800);            //      8,192 B
  unsigned short* Nhi = (unsigned short*)(ws + 8404992);            //    262,144 B
  unsigned short* Nlo = (unsigned short*)(ws + 8667136);            //    262,144 B
  float2* spart       = (float2*)(ws + 8929280);                    //      8,192 B
  float* attQ         = (float*)(ws + 8937472);                     //  1,048,576 B

  k0_prep<<<dim3(16), 256, 0, stream>>>(wphi, wg, Whi, Wlo);
  k1_att<<<dim3(128, 8), 256, 0, stream>>>(x, Whi, Wlo, attP, spart);
  k3a_reduce<<<dim3(256), 256, 0, stream>>>(attP, attQ);
  k3b_nmat<<<dim3(8), 1024, 0, stream>>>(attQ, spart, wm, wtheta, Nhi, Nlo);
  k5_out<<<dim3(128, 8), 512, 0, stream>>>(x, Nhi, Nlo, out);
}

// Round 16
// 108.887 us; speedup vs baseline: 1.2237x; 1.0053x over previous
//
#include <hip/hip_runtime.h>

typedef __attribute__((ext_vector_type(8))) short short8;
typedef __attribute__((ext_vector_type(4))) float f32x4;
typedef __attribute__((ext_vector_type(4))) unsigned int uint4v;

#define HW 65536
#define NPOS 32768

__device__ __forceinline__ unsigned short f2bf(float f) {
  unsigned u = __builtin_bit_cast(unsigned, f);
  u += 0x7fffu + ((u >> 16) & 1u);
  return (unsigned short)(u >> 16);
}
__device__ __forceinline__ float bf2f(unsigned short h) {
  unsigned u = (unsigned)h << 16;
  return __builtin_bit_cast(float, u);
}
__device__ __forceinline__ int slot4(int r) { return (r ^ (r >> 2)) & 15; }
// 16B fragment from 8B-aligned LDS (row stride 136B) as two b64 reads
__device__ __forceinline__ short8 ld_e16(const unsigned short* p) {
  const uint2 a = *(const uint2*)p;
  const uint2 b = *(const uint2*)(p + 4);
  uint4v u = {a.x, a.y, b.x, b.y};
  return __builtin_bit_cast(short8, u);
}

// ---------------------------------------------------------------------------
// k1: FUSED conv + exp + att, atomic-free (R15 proven config, 109.5 µs).
// k0 folded in: each block splits W fp32 -> bf16 hi/lo in registers
// (16 KB L2-broadcast read, ~200 cycles) - one fewer launch + dependency.
// Grid (128, 8). Block = 4 waves / 256 thr, owns 256 view-cols = 4 subtiles.
// E double-buffered in LDS (2 x 17.4 KB), ONE barrier/subtile; prefetch of
// the next subtile's x issues before the barrier. bf16 attP partials.
// ---------------------------------------------------------------------------
__global__ __launch_bounds__(256) void k1_att(
    const float* __restrict__ x, const float* __restrict__ wphi,
    const float* __restrict__ wg, unsigned short* __restrict__ attP,
    float2* __restrict__ spart)
{
  __shared__ unsigned short E[2][128 * 68];   // [buf][row][68]; rows 0-63 Ep, 64-127 Eg
  __shared__ float2 rbuf[4];

  const int tid = threadIdx.x;
  const int b = blockIdx.y, blk = blockIdx.x;
  const int w = tid >> 6, l = tid & 63;
  const int lr = l & 15, g = l >> 4;
  const int h = w >> 1, qb = (w & 1) * 2;     // conv: half h, quarters qb, qb+1
  const int n0 = blk * 256;
  const float* xb = x + (size_t)b * 64 * HW + (size_t)h * NPOS;

  // conv B-fragments: split W fp32 -> hi/lo in registers (k0 folded in)
  short8 wbh[4][2], wbl[4][2];
  #pragma unroll
  for (int cht = 0; cht < 4; ++cht) {
    const int u = cht * 16 + lr;
    const float* wrow = (u < 32) ? (wphi + u * 64) : (wg + (u - 32) * 64);
    #pragma unroll
    for (int ks = 0; ks < 2; ++ks)
      #pragma unroll
      for (int e = 0; e < 8; ++e) {
        const float wv = wrow[ks * 32 + g * 8 + e];
        const unsigned short hi = f2bf(wv);
        wbh[cht][ks][e] = (short)hi;
        wbl[cht][ks][e] = (short)f2bf(wv - bf2f(hi));
      }
  }

  f32x4 aacc[4] = {{0.f,0.f,0.f,0.f},{0.f,0.f,0.f,0.f},{0.f,0.f,0.f,0.f},{0.f,0.f,0.f,0.f}};
  float ssp = 0.f, ssg = 0.f;

  // A-fragment loads: lane (lr,g), element e -> channel (e>>3)*32+g*8+(e&7),
  // pos = base + lr (16 consecutive cols per 16-lane group: coalesced)
  float xvA[16], xvB[16];
  #pragma unroll
  for (int e = 0; e < 16; ++e) {
    const size_t co = (size_t)((e >> 3) * 32 + g * 8 + (e & 7)) * HW;
    xvA[e] = xb[co + n0 + (qb + 0) * 16 + lr];
    xvB[e] = xb[co + n0 + (qb + 1) * 16 + lr];
  }

  for (int t = 0; t < 4; ++t) {
    const int buf = t & 1;
    // two pos-tiles: convert, conv-MFMA, exp, E write
    #pragma unroll
    for (int j = 0; j < 2; ++j) {
      const float* xv = j ? xvB : xvA;
      short8 ah[2];
      #pragma unroll
      for (int ks = 0; ks < 2; ++ks)
        #pragma unroll
        for (int e = 0; e < 8; ++e)
          ah[ks][e] = (short)f2bf(xv[ks * 8 + e]);
      f32x4 cacc[4] = {{0.f,0.f,0.f,0.f},{0.f,0.f,0.f,0.f},{0.f,0.f,0.f,0.f},{0.f,0.f,0.f,0.f}};
      #pragma unroll
      for (int cht = 0; cht < 4; ++cht)
        #pragma unroll
        for (int ks = 0; ks < 2; ++ks) {
          cacc[cht] = __builtin_amdgcn_mfma_f32_16x16x32_bf16(ah[ks], wbh[cht][ks], cacc[cht], 0, 0, 0);
          cacc[cht] = __builtin_amdgcn_mfma_f32_16x16x32_bf16(ah[ks], wbl[cht][ks], cacc[cht], 0, 0, 0);
        }
      // exp + E[buf] write: lane holds D[pos=g*4+r][ch=lr] -> row f(ch), 4 consec n
      #pragma unroll
      for (int cht = 0; cht < 4; ++cht) {
        const float e0 = __expf(cacc[cht][0]);
        const float e1 = __expf(cacc[cht][1]);
        const float e2 = __expf(cacc[cht][2]);
        const float e3 = __expf(cacc[cht][3]);
        if (cht < 2) ssp += (e0 + e1) + (e2 + e3);
        else         ssg += (e0 + e1) + (e2 + e3);
        const int row = ((cht >= 2) ? 64 : 0) + 2 * ((cht & 1) * 16 + lr) + h;
        uint2 pk;
        pk.x = (unsigned)f2bf(e0) | ((unsigned)f2bf(e1) << 16);
        pk.y = (unsigned)f2bf(e2) | ((unsigned)f2bf(e3) << 16);
        *(uint2*)&E[buf][row * 68 + (qb + j) * 16 + g * 4] = pk;
      }
    }
    // prefetch next subtile BEFORE the barrier (drain overlaps sibling-wait)
    if (t < 3) {
      const int nn = n0 + (t + 1) * 64;
      #pragma unroll
      for (int e = 0; e < 16; ++e) {
        const size_t co = (size_t)((e >> 3) * 32 + g * 8 + (e & 7)) * HW;
        xvA[e] = xb[co + nn + (qb + 0) * 16 + lr];
        xvB[e] = xb[co + nn + (qb + 1) * 16 + lr];
      }
    }
    __syncthreads();   // E[buf] complete; E[buf^1] readers (t-1) done

    // att: wave owns row-block w vs col-blocks 0..3, K=64 (2 ksteps)
    #pragma unroll
    for (int ks = 0; ks < 2; ++ks) {
      const short8 ag = ld_e16(&E[buf][(64 + w * 16 + lr) * 68 + ks * 32 + g * 8]);
      #pragma unroll
      for (int j = 0; j < 4; ++j) {
        const short8 bp = ld_e16(&E[buf][(j * 16 + lr) * 68 + ks * 32 + g * 8]);
        aacc[j] = __builtin_amdgcn_mfma_f32_16x16x32_bf16(ag, bp, aacc[j], 0, 0, 0);
      }
    }
  }

  // flush att partials as bf16: lane holds att[w*16+g*4+r][j*16+lr]
  unsigned short* ap = attP + (size_t)(b * 128 + blk) * 4096;
  #pragma unroll
  for (int j = 0; j < 4; ++j)
    #pragma unroll
    for (int r = 0; r < 4; ++r)
      ap[(w * 16 + g * 4 + r) * 64 + j * 16 + lr] = f2bf(aacc[j][r]);

  // softmax denominators -> per-block slot (NO atomics)
  #pragma unroll
  for (int off = 32; off > 0; off >>= 1) {
    ssp += __shfl_down(ssp, off);
    ssg += __shfl_down(ssg, off);
  }
  if (l == 0) rbuf[w] = make_float2(ssp, ssg);
  __syncthreads();
  if (tid == 0) {
    float a = 0.f, c = 0.f;
    #pragma unroll
    for (int i = 0; i < 4; ++i) { a += rbuf[i].x; c += rbuf[i].y; }
    spart[b * 128 + blk] = make_float2(a, c);
  }
}

// ---------------------------------------------------------------------------
// k3a: partial-reduce bf16 att partials 128 -> 8 (fp32) per batch, e-split
// 4x for chip-wide spread. Grid (256): b = blk>>5, part = (blk>>2)&7, es = blk&3.
// ---------------------------------------------------------------------------
__global__ __launch_bounds__(256) void k3a_reduce(
    const unsigned short* __restrict__ attP, float* __restrict__ attQ)
{
  const int b = blockIdx.x >> 5, part = (blockIdx.x >> 2) & 7, es = blockIdx.x & 3;
  const unsigned short* p = attP + (size_t)(b * 128 + part * 16) * 4096 + es * 1024;
  float* q = attQ + (size_t)(b * 8 + part) * 4096 + es * 1024;
  for (int e = threadIdx.x; e < 1024; e += 256) {
    float s0 = 0.f, s1 = 0.f, s2 = 0.f, s3 = 0.f;
    #pragma unroll
    for (int k = 0; k < 16; k += 4) {
      s0 += bf2f(p[(size_t)k * 4096 + e]);
      s1 += bf2f(p[(size_t)(k + 1) * 4096 + e]);
      s2 += bf2f(p[(size_t)(k + 2) * 4096 + e]);
      s3 += bf2f(p[(size_t)(k + 3) * 4096 + e]);
    }
    q[e] = (s0 + s1) + (s2 + s3);
  }
}

// ---------------------------------------------------------------------------
// k3b: reduce spart (128 float2/batch) -> scale; final att reduce; N mats.
// ---------------------------------------------------------------------------
__global__ __launch_bounds__(1024) void k3b_nmat(
    const float* __restrict__ attQ, const float2* __restrict__ spart,
    const float* __restrict__ wm, const float* __restrict__ wtheta,
    unsigned short* __restrict__ Nhi, unsigned short* __restrict__ Nlo)
{
  __shared__ float att_s[4096];
  __shared__ float Mp[2][64][64];
  __shared__ float wms[64][32];
  __shared__ float wts[32][64];
  __shared__ float sP[128], sG[128];
  const int tid = threadIdx.x;
  const int b = blockIdx.x;

  if (tid < 512) {
    if (tid < 128) {
      const float2 v = spart[b * 128 + tid];
      sP[tid] = v.x; sG[tid] = v.y;
    }
    if (tid < 256) { for (int k = tid; k < 2048; k += 256) wms[k >> 5][k & 31] = wm[k]; }
    else           { for (int k = tid - 256; k < 2048; k += 256) wts[k >> 6][k & 63] = wtheta[k]; }
  }
  for (int e = tid; e < 4096; e += 1024) {
    const float* p = attQ + (size_t)b * 8 * 4096 + e;
    float s = 0.f;
    #pragma unroll
    for (int q = 0; q < 8; ++q) s += p[(size_t)q * 4096];
    att_s[e] = s;
  }
  __syncthreads();
  #pragma unroll
  for (int s = 64; s > 0; s >>= 1) {
    if (tid < s) { sP[tid] += sP[tid + s]; sG[tid] += sG[tid + s]; }
    __syncthreads();
  }
  for (int idx = tid; idx < 8192; idx += 1024) {
    const int h = idx >> 12, o = (idx >> 6) & 63, d = idx & 63;
    float s = 0.f;
    #pragma unroll
    for (int i = 0; i < 32; ++i)
      s = __builtin_fmaf(wms[o][i], att_s[(2 * i + h) * 64 + d], s);
    Mp[h][o][d] = s;
  }
  __syncthreads();
  const float scale = 1.f / (sP[0] * sG[0]);
  for (int idx = tid; idx < 16384; idx += 1024) {
    const int oo = idx >> 7, cc = idx & 127;
    const int h = oo >> 6, o = oo & 63, e = cc >> 6, c = cc & 63;
    float s = 0.f;
    #pragma unroll
    for (int j = 0; j < 32; ++j)
      s = __builtin_fmaf(Mp[h][o][2 * j + e], wts[j][c], s);
    s *= scale;
    const unsigned short hi = f2bf(s);
    Nhi[(size_t)b * 16384 + idx] = hi;
    Nlo[(size_t)b * 16384 + idx] = f2bf(s - bf2f(hi));
  }
}

// ---------------------------------------------------------------------------
// k5: out[b][o][h*NPOS+n] = sum_cc N[b][h*64+o][cc] * x[b][cc&63][(cc>>6)*NPOS+n]
// Grid (128, 8): block owns 256 n-cols = 4 tiles of 64; Xh double-buffered,
// ONE barrier/tile; N B-fragments loaded ONCE per block.
// A = x [n][cc], B = N rows (oo) -> lane stores float4 of consecutive n.
// ---------------------------------------------------------------------------
__global__ __launch_bounds__(512) void k5_out(
    const float* __restrict__ x, const unsigned short* __restrict__ Nhi,
    const unsigned short* __restrict__ Nlo, float* __restrict__ out)
{
  __shared__ unsigned short Xh[2][64 * 128];   // [buf][n][cc], cc ^ (slot4(n)<<3)
  const int tid = threadIdx.x;
  const int b = blockIdx.y, n0 = blockIdx.x * 256;
  const int w = tid >> 6, l = tid & 63;
  const int lr = l & 15, g = l >> 4;

  // B-fragments: N rows oo = w*16 + lr, K=128 (4 ksteps), hi/lo — loaded once
  short8 bh[4], bl[4];
  #pragma unroll
  for (int ks = 0; ks < 4; ++ks) {
    const size_t off = (size_t)b * 16384 + (size_t)(w * 16 + lr) * 128 + ks * 32 + g * 8;
    bh[ks] = *(const short8*)(Nhi + off);
    bl[ks] = *(const short8*)(Nlo + off);
  }

  const int ccb = w * 16;
  const int c0 = ccb & 63, e0 = ccb >> 6;
  const float* xp = x + (size_t)b * 64 * HW + (size_t)c0 * HW
                  + (size_t)e0 * NPOS + n0 + l;
  const int s8 = slot4(l) << 3;
  const int oo = w * 16 + lr;
  float* op0 = out + (size_t)b * 64 * HW + (size_t)(oo & 63) * HW
             + (size_t)(oo >> 6) * NPOS + n0 + g * 4;

  // prologue: tile 0 loads (lane spans n: coalesced)
  float v[16];
  #pragma unroll
  for (int i = 0; i < 16; ++i) v[i] = xp[(size_t)i * HW];

  for (int t = 0; t < 4; ++t) {
    const int buf = t & 1;
    // pack + stage current tile
    {
      short8 pa, pb;
      #pragma unroll
      for (int i = 0; i < 8; ++i) {
        pa[i] = (short)f2bf(v[i]);
        pb[i] = (short)f2bf(v[8 + i]);
      }
      *(short8*)&Xh[buf][l * 128 + (ccb ^ s8)] = pa;
      *(short8*)&Xh[buf][l * 128 + ((ccb + 8) ^ s8)] = pb;
    }
    // prefetch next tile before the barrier
    if (t < 3) {
      #pragma unroll
      for (int i = 0; i < 16; ++i) v[i] = xp[(size_t)i * HW + (t + 1) * 64];
    }
    __syncthreads();   // Xh[buf] staged; Xh[buf^1] readers (t-1) done

    float* op = op0 + t * 64;
    #pragma unroll
    for (int ct4 = 0; ct4 < 4; ++ct4) {
      f32x4 acc = {0.f, 0.f, 0.f, 0.f};
      const int arow = ct4 * 16 + lr;
      const int sw = slot4(arow) << 3;
      #pragma unroll
      for (int ks = 0; ks < 4; ++ks) {
        const short8 av = *(const short8*)&Xh[buf][arow * 128 + ((ks * 32 + g * 8) ^ sw)];
        acc = __builtin_amdgcn_mfma_f32_16x16x32_bf16(av, bh[ks], acc, 0, 0, 0);
        acc = __builtin_amdgcn_mfma_f32_16x16x32_bf16(av, bl[ks], acc, 0, 0, 0);
      }
      *(float4*)(op + ct4 * 16) = *(float4*)&acc;
    }
  }
}

// ---------------------------------------------------------------------------
extern "C" void kernel_launch(void* const* d_in, const int* in_sizes, int n_in,
                              void* d_out, int out_size, void* d_ws, size_t ws_size,
                              hipStream_t stream)
{
  const float* x      = (const float*)d_in[0];
  const float* wphi   = (const float*)d_in[1];
  const float* wtheta = (const float*)d_in[2];
  const float* wg     = (const float*)d_in[3];
  const float* wm     = (const float*)d_in[4];
  float* out = (float*)d_out;

  char* ws = (char*)d_ws;
  unsigned short* attP = (unsigned short*)ws;                       //  8,388,608 B
  unsigned short* Nhi = (unsigned short*)(ws + 8388608);            //    262,144 B
  unsigned short* Nlo = (unsigned short*)(ws + 8650752);            //    262,144 B
  float2* spart       = (float2*)(ws + 8912896);                    //      8,192 B
  float* attQ         = (float*)(ws + 8921088);                     //  1,048,576 B

  k1_att<<<dim3(128, 8), 256, 0, stream>>>(x, wphi, wg, attP, spart);
  k3a_reduce<<<dim3(256), 256, 0, stream>>>(attP, attQ);
  k3b_nmat<<<dim3(8), 1024, 0, stream>>>(attQ, spart, wm, wtheta, Nhi, Nlo);
  k5_out<<<dim3(128, 8), 512, 0, stream>>>(x, Nhi, Nlo, out);
}